// Round 1
// baseline (413.022 us; speedup 1.0000x reference)
//
#include <hip/hip_runtime.h>
#include <hip/hip_bf16.h>
#include <cstdint>

#define NN 50000
#define NE 800000
#define HD 128
#define OD 64
#define NG 64
#define SCAN_CHUNK 196
#define SCAN_BLOCKS 256

// ---------- degree / CSR build ----------

__global__ void k_count(const int* __restrict__ dst, int* __restrict__ cnt) {
    int e = blockIdx.x * 256 + threadIdx.x;
    if (e < NE) atomicAdd(&cnt[dst[e]], 1);
}

__global__ void k_dinv(const int* __restrict__ cnt, float* __restrict__ dinv) {
    int v = blockIdx.x * 256 + threadIdx.x;
    if (v < NN) dinv[v] = rsqrtf((float)(cnt[v] + 1));  // +1 self-loop
}

__global__ void k_chunksum(const int* __restrict__ cnt, int* __restrict__ chunksum) {
    __shared__ int red[256];
    int t = threadIdx.x;
    int i = blockIdx.x * SCAN_CHUNK + t;
    int v = (t < SCAN_CHUNK && i < NN) ? cnt[i] : 0;
    red[t] = v; __syncthreads();
    for (int off = 128; off > 0; off >>= 1) {
        if (t < off) red[t] += red[t + off];
        __syncthreads();
    }
    if (t == 0) chunksum[blockIdx.x] = red[0];
}

__global__ void k_scanchunks(const int* __restrict__ chunksum, int* __restrict__ chunkoff,
                             int* __restrict__ row_start) {
    __shared__ int s[256];
    int t = threadIdx.x;
    int v = chunksum[t];
    s[t] = v; __syncthreads();
    for (int off = 1; off < 256; off <<= 1) {
        int u = (t >= off) ? s[t - off] : 0;
        __syncthreads();
        s[t] += u;
        __syncthreads();
    }
    chunkoff[t] = s[t] - v;          // exclusive
    if (t == 255) row_start[NN] = s[255];
}

__global__ void k_scanwrite(const int* __restrict__ cnt, const int* __restrict__ chunkoff,
                            int* __restrict__ row_start) {
    __shared__ int s[256];
    int t = threadIdx.x;
    int i = blockIdx.x * SCAN_CHUNK + t;
    int v = (t < SCAN_CHUNK && i < NN) ? cnt[i] : 0;
    s[t] = v; __syncthreads();
    for (int off = 1; off < 256; off <<= 1) {
        int u = (t >= off) ? s[t - off] : 0;
        __syncthreads();
        s[t] += u;
        __syncthreads();
    }
    if (t < SCAN_CHUNK && i < NN) row_start[i] = chunkoff[blockIdx.x] + s[t] - v;
}

__global__ void k_fill(const int* __restrict__ src, const int* __restrict__ dst,
                       const int* __restrict__ row_start, int* __restrict__ fill_cnt,
                       int* __restrict__ csr) {
    int e = blockIdx.x * 256 + threadIdx.x;
    if (e < NE) {
        int d = dst[e];
        int slot = row_start[d] + atomicAdd(&fill_cnt[d], 1);
        csr[slot] = src[e];
    }
}

// ---------- GEMM: out[r] = (X[r] @ W) * dinv[r],  X [nrows][128], W [128][128] ----------

__global__ __launch_bounds__(256, 2) void k_gemm(const float* __restrict__ X,
                                                 const float* __restrict__ W,
                                                 const float* __restrict__ dinv,
                                                 float* __restrict__ out, int nrows) {
    __shared__ float wl[128 * 128];   // 64 KB
    __shared__ float xl[32 * 128];    // 16 KB
    {
        float4* wl4 = (float4*)wl;
        const float4* W4 = (const float4*)W;
        for (int i = threadIdx.x; i < 128 * 32; i += 256) wl4[i] = W4[i];
    }
    const int rg = threadIdx.x >> 5;   // 0..7 : rows rg*4 .. rg*4+3
    const int cg = threadIdx.x & 31;   // cols cg*4 .. cg*4+3
    const int ntiles = (nrows + 31) >> 5;
    for (int tile = blockIdx.x; tile < ntiles; tile += gridDim.x) {
        const int row0 = tile << 5;
        __syncthreads();   // xl reuse guard (also covers first-iter W visibility combined w/ next)
        for (int i = threadIdx.x; i < 32 * 32; i += 256) {
            int rr = row0 + (i >> 5);
            ((float4*)xl)[i] = (rr < nrows) ? ((const float4*)X)[rr * 32 + (i & 31)]
                                            : make_float4(0.f, 0.f, 0.f, 0.f);
        }
        __syncthreads();
        float acc[4][4];
#pragma unroll
        for (int a = 0; a < 4; ++a)
#pragma unroll
            for (int b = 0; b < 4; ++b) acc[a][b] = 0.f;
        const float4* wl4 = (const float4*)wl;
        const float4* xl4 = (const float4*)xl;
#pragma unroll 4
        for (int kq = 0; kq < 32; ++kq) {
            float4 w0 = wl4[(4 * kq + 0) * 32 + cg];
            float4 w1 = wl4[(4 * kq + 1) * 32 + cg];
            float4 w2 = wl4[(4 * kq + 2) * 32 + cg];
            float4 w3 = wl4[(4 * kq + 3) * 32 + cg];
#pragma unroll
            for (int r = 0; r < 4; ++r) {
                float4 xv = xl4[(rg * 4 + r) * 32 + kq];
                acc[r][0] += xv.x * w0.x + xv.y * w1.x + xv.z * w2.x + xv.w * w3.x;
                acc[r][1] += xv.x * w0.y + xv.y * w1.y + xv.z * w2.y + xv.w * w3.y;
                acc[r][2] += xv.x * w0.z + xv.y * w1.z + xv.z * w2.z + xv.w * w3.z;
                acc[r][3] += xv.x * w0.w + xv.y * w1.w + xv.z * w2.w + xv.w * w3.w;
            }
        }
#pragma unroll
        for (int r = 0; r < 4; ++r) {
            int rr = row0 + rg * 4 + r;
            if (rr < nrows) {
                float dv = dinv[rr];
                float4 o;
                o.x = acc[r][0] * dv; o.y = acc[r][1] * dv;
                o.z = acc[r][2] * dv; o.w = acc[r][3] * dv;
                ((float4*)out)[rr * 32 + cg] = o;
            }
        }
    }
}

// ---------- aggregation: out[v] = relu(dinv[v]*(hp[v] + sum_{s->v} hp[s]) + b) ----------

__global__ void k_agg(const float* __restrict__ hp, const int* __restrict__ row_start,
                      const int* __restrict__ csr, const float* __restrict__ dinv,
                      const float* __restrict__ bias, float* __restrict__ out) {
    int wid = threadIdx.x >> 6, lane = threadIdx.x & 63;
    int v = blockIdx.x * 4 + wid;
    if (v >= NN) return;
    const float2* hp2 = (const float2*)hp;
    float2 acc = hp2[v * 64 + lane];           // self loop
    int beg = row_start[v], end = row_start[v + 1];
    int e = beg;
    if (e < end) {
        int s = csr[e];
        while (++e < end) {
            int sn = csr[e];                   // prefetch next index
            float2 m = hp2[s * 64 + lane];
            acc.x += m.x; acc.y += m.y;
            s = sn;
        }
        float2 m = hp2[s * 64 + lane];
        acc.x += m.x; acc.y += m.y;
    }
    float dv = dinv[v];
    float2 bb = ((const float2*)bias)[lane];
    float2 o;
    o.x = fmaxf(acc.x * dv + bb.x, 0.f);
    o.y = fmaxf(acc.y * dv + bb.y, 0.f);
    ((float2*)out)[v * 64 + lane] = o;
}

// ---------- fused mean-pool + linear head ----------

__global__ __launch_bounds__(256) void k_pool(const float* __restrict__ h,
                                              const int* __restrict__ batch,
                                              const float* __restrict__ Wl,
                                              const float* __restrict__ bl,
                                              float* __restrict__ out) {
    int g = blockIdx.x, t = threadIdx.x;
    __shared__ int se[2];
    __shared__ float part[256];
    __shared__ float pooled[128];
    if (t < 2) {
        int target = g + t;   // lower_bound(batch, target)
        int lo = 0, hi = NN;
        while (lo < hi) {
            int mid = (lo + hi) >> 1;
            if (batch[mid] < target) lo = mid + 1; else hi = mid;
        }
        se[t] = lo;
    }
    __syncthreads();
    int start = se[0], end = se[1];
    int col = t & 127, half = t >> 7;
    float acc = 0.f;
    for (int v = start + half; v < end; v += 2) acc += h[v * 128 + col];
    part[t] = acc; __syncthreads();
    if (t < 128) {
        float s = part[t] + part[t + 128];
        float c = (end > start) ? (float)(end - start) : 1.f;
        pooled[t] = s / c;
    }
    __syncthreads();
    if (t < OD) {
        float o = bl[t];
        for (int k = 0; k < 128; ++k) o += pooled[k] * Wl[k * OD + t];
        out[g * OD + t] = o;
    }
}

// ---------- launcher ----------

extern "C" void kernel_launch(void* const* d_in, const int* in_sizes, int n_in,
                              void* d_out, int out_size, void* d_ws, size_t ws_size,
                              hipStream_t stream) {
    const float* x   = (const float*)d_in[0];
    const int*   ei  = (const int*)d_in[1];
    const int*   bat = (const int*)d_in[2];
    const float* W1  = (const float*)d_in[3];
    const float* b1  = (const float*)d_in[4];
    const float* W2  = (const float*)d_in[5];
    const float* b2  = (const float*)d_in[6];
    const float* Wl  = (const float*)d_in[7];
    const float* bl  = (const float*)d_in[8];
    float* out = (float*)d_out;
    const int* src = ei;
    const int* dst = ei + NE;

    char* w = (char*)d_ws;
    size_t off = 0;
    auto alloc = [&](size_t bytes) -> char* {
        char* p = w + off;
        off = (off + bytes + 255) & ~(size_t)255;
        return p;
    };
    int*   cnt       = (int*)alloc(NN * 4);
    int*   fill      = (int*)alloc(NN * 4);
    float* dinv      = (float*)alloc(NN * 4);
    int*   row_start = (int*)alloc((NN + 1) * 4);
    int*   chunksum  = (int*)alloc(256 * 4);
    int*   chunkoff  = (int*)alloc(256 * 4);
    int*   csr       = (int*)alloc((size_t)NE * 4);
    float* bufA      = (float*)alloc((size_t)NN * HD * 4);
    float* bufB      = (float*)alloc((size_t)NN * HD * 4);

    hipMemsetAsync(cnt, 0, NN * 4, stream);
    hipMemsetAsync(fill, 0, NN * 4, stream);

    k_count<<<(NE + 255) / 256, 256, 0, stream>>>(dst, cnt);
    k_dinv<<<(NN + 255) / 256, 256, 0, stream>>>(cnt, dinv);
    k_chunksum<<<SCAN_BLOCKS, 256, 0, stream>>>(cnt, chunksum);
    k_scanchunks<<<1, 256, 0, stream>>>(chunksum, chunkoff, row_start);
    k_scanwrite<<<SCAN_BLOCKS, 256, 0, stream>>>(cnt, chunkoff, row_start);
    k_fill<<<(NE + 255) / 256, 256, 0, stream>>>(src, dst, row_start, fill, csr);

    // conv1: h' = (x@W1)*dinv  ->  bufA ; agg+bias+relu -> bufB
    k_gemm<<<512, 256, 0, stream>>>(x, W1, dinv, bufA, NN);
    k_agg<<<(NN + 3) / 4, 256, 0, stream>>>(bufA, row_start, csr, dinv, b1, bufB);
    // conv2
    k_gemm<<<512, 256, 0, stream>>>(bufB, W2, dinv, bufA, NN);
    k_agg<<<(NN + 3) / 4, 256, 0, stream>>>(bufA, row_start, csr, dinv, b2, bufB);
    // pool + head
    k_pool<<<NG, 256, 0, stream>>>(bufB, bat, Wl, bl, out);
}

// Round 2
// 334.093 us; speedup vs baseline: 1.2363x; 1.2363x over previous
//
#include <hip/hip_runtime.h>
#include <hip/hip_bf16.h>
#include <cstdint>

#define NN 50000
#define NE 800000
#define HD 128
#define OD 64
#define NG 64
#define SCAN_CHUNK 196
#define SCAN_BLOCKS 256
#define POOL_ROWS 256

// ---------- degree / CSR build ----------

__global__ void k_count(const int* __restrict__ dst, int* __restrict__ cnt) {
    int e = blockIdx.x * 256 + threadIdx.x;
    if (e < NE) atomicAdd(&cnt[dst[e]], 1);
}

__global__ void k_dinv(const int* __restrict__ cnt, float* __restrict__ dinv) {
    int v = blockIdx.x * 256 + threadIdx.x;
    if (v < NN) dinv[v] = rsqrtf((float)(cnt[v] + 1));  // +1 self-loop
}

__global__ void k_chunksum(const int* __restrict__ cnt, int* __restrict__ chunksum) {
    __shared__ int red[256];
    int t = threadIdx.x;
    int i = blockIdx.x * SCAN_CHUNK + t;
    int v = (t < SCAN_CHUNK && i < NN) ? cnt[i] : 0;
    red[t] = v; __syncthreads();
    for (int off = 128; off > 0; off >>= 1) {
        if (t < off) red[t] += red[t + off];
        __syncthreads();
    }
    if (t == 0) chunksum[blockIdx.x] = red[0];
}

__global__ void k_scanchunks(const int* __restrict__ chunksum, int* __restrict__ chunkoff,
                             int* __restrict__ row_start) {
    __shared__ int s[256];
    int t = threadIdx.x;
    int v = chunksum[t];
    s[t] = v; __syncthreads();
    for (int off = 1; off < 256; off <<= 1) {
        int u = (t >= off) ? s[t - off] : 0;
        __syncthreads();
        s[t] += u;
        __syncthreads();
    }
    chunkoff[t] = s[t] - v;          // exclusive
    if (t == 255) row_start[NN] = s[255];
}

__global__ void k_scanwrite(const int* __restrict__ cnt, const int* __restrict__ chunkoff,
                            int* __restrict__ row_start) {
    __shared__ int s[256];
    int t = threadIdx.x;
    int i = blockIdx.x * SCAN_CHUNK + t;
    int v = (t < SCAN_CHUNK && i < NN) ? cnt[i] : 0;
    s[t] = v; __syncthreads();
    for (int off = 1; off < 256; off <<= 1) {
        int u = (t >= off) ? s[t - off] : 0;
        __syncthreads();
        s[t] += u;
        __syncthreads();
    }
    if (t < SCAN_CHUNK && i < NN) row_start[i] = chunkoff[blockIdx.x] + s[t] - v;
}

__global__ void k_fill(const int* __restrict__ src, const int* __restrict__ dst,
                       const int* __restrict__ row_start, int* __restrict__ fill_cnt,
                       int* __restrict__ csr) {
    int e = blockIdx.x * 256 + threadIdx.x;
    if (e < NE) {
        int d = dst[e];
        int slot = row_start[d] + atomicAdd(&fill_cnt[d], 1);
        csr[slot] = src[e];
    }
}

// ---------- GEMM: out[r] = (X[r] @ W) * dinv[r],  X [nrows][128], W [128][128] ----------

__global__ __launch_bounds__(256, 2) void k_gemm(const float* __restrict__ X,
                                                 const float* __restrict__ W,
                                                 const float* __restrict__ dinv,
                                                 float* __restrict__ out, int nrows) {
    __shared__ float wl[128 * 128];   // 64 KB
    __shared__ float xl[32 * 128];    // 16 KB
    {
        float4* wl4 = (float4*)wl;
        const float4* W4 = (const float4*)W;
        for (int i = threadIdx.x; i < 128 * 32; i += 256) wl4[i] = W4[i];
    }
    const int rg = threadIdx.x >> 5;   // 0..7 : rows rg*4 .. rg*4+3
    const int cg = threadIdx.x & 31;   // cols cg*4 .. cg*4+3
    const int ntiles = (nrows + 31) >> 5;
    for (int tile = blockIdx.x; tile < ntiles; tile += gridDim.x) {
        const int row0 = tile << 5;
        __syncthreads();
        for (int i = threadIdx.x; i < 32 * 32; i += 256) {
            int rr = row0 + (i >> 5);
            ((float4*)xl)[i] = (rr < nrows) ? ((const float4*)X)[rr * 32 + (i & 31)]
                                            : make_float4(0.f, 0.f, 0.f, 0.f);
        }
        __syncthreads();
        float acc[4][4];
#pragma unroll
        for (int a = 0; a < 4; ++a)
#pragma unroll
            for (int b = 0; b < 4; ++b) acc[a][b] = 0.f;
        const float4* wl4 = (const float4*)wl;
        const float4* xl4 = (const float4*)xl;
#pragma unroll 4
        for (int kq = 0; kq < 32; ++kq) {
            float4 w0 = wl4[(4 * kq + 0) * 32 + cg];
            float4 w1 = wl4[(4 * kq + 1) * 32 + cg];
            float4 w2 = wl4[(4 * kq + 2) * 32 + cg];
            float4 w3 = wl4[(4 * kq + 3) * 32 + cg];
#pragma unroll
            for (int r = 0; r < 4; ++r) {
                float4 xv = xl4[(rg * 4 + r) * 32 + kq];
                acc[r][0] += xv.x * w0.x + xv.y * w1.x + xv.z * w2.x + xv.w * w3.x;
                acc[r][1] += xv.x * w0.y + xv.y * w1.y + xv.z * w2.y + xv.w * w3.y;
                acc[r][2] += xv.x * w0.z + xv.y * w1.z + xv.z * w2.z + xv.w * w3.z;
                acc[r][3] += xv.x * w0.w + xv.y * w1.w + xv.z * w2.w + xv.w * w3.w;
            }
        }
#pragma unroll
        for (int r = 0; r < 4; ++r) {
            int rr = row0 + rg * 4 + r;
            if (rr < nrows) {
                float dv = dinv[rr];
                float4 o;
                o.x = acc[r][0] * dv; o.y = acc[r][1] * dv;
                o.z = acc[r][2] * dv; o.w = acc[r][3] * dv;
                ((float4*)out)[rr * 32 + cg] = o;
            }
        }
    }
}

// ---------- aggregation: out[v] = relu(dinv[v]*(hp[v] + sum_{s->v} hp[s]) + b) ----------

__global__ void k_agg(const float* __restrict__ hp, const int* __restrict__ row_start,
                      const int* __restrict__ csr, const float* __restrict__ dinv,
                      const float* __restrict__ bias, float* __restrict__ out) {
    int wid = threadIdx.x >> 6, lane = threadIdx.x & 63;
    int v = blockIdx.x * 4 + wid;
    if (v >= NN) return;
    const float2* hp2 = (const float2*)hp;
    float2 acc = hp2[v * 64 + lane];           // self loop
    int beg = row_start[v], end = row_start[v + 1];
    int e = beg;
    if (e < end) {
        int s = csr[e];
        while (++e < end) {
            int sn = csr[e];                   // prefetch next index
            float2 m = hp2[s * 64 + lane];
            acc.x += m.x; acc.y += m.y;
            s = sn;
        }
        float2 m = hp2[s * 64 + lane];
        acc.x += m.x; acc.y += m.y;
    }
    float dv = dinv[v];
    float2 bb = ((const float2*)bias)[lane];
    float2 o;
    o.x = fmaxf(acc.x * dv + bb.x, 0.f);
    o.y = fmaxf(acc.y * dv + bb.y, 0.f);
    ((float2*)out)[v * 64 + lane] = o;
}

// ---------- pooling stage 1: node-parallel segment-sum into pooled[64][128] ----------

__global__ __launch_bounds__(256) void k_pool1(const float* __restrict__ h,
                                               const int* __restrict__ batch,
                                               float* __restrict__ pooled) {
    __shared__ int bl[POOL_ROWS];
    const int row0 = blockIdx.x * POOL_ROWS;
    const int rend = min(row0 + POOL_ROWS, NN);
    const int nrows = rend - row0;
    for (int i = threadIdx.x; i < nrows; i += 256) bl[i] = batch[row0 + i];
    __syncthreads();
    const int col2 = threadIdx.x & 63;      // float2 column
    const int rp   = threadIdx.x >> 6;      // 0..3
    const float2* h2 = (const float2*)h;
    float2 acc = make_float2(0.f, 0.f);
    int curg = -1;
    for (int i = rp; i < nrows; i += 4) {
        int g = bl[i];
        if (g != curg) {
            if (curg >= 0) {
                atomicAdd(&pooled[curg * 128 + 2 * col2], acc.x);
                atomicAdd(&pooled[curg * 128 + 2 * col2 + 1], acc.y);
            }
            acc = make_float2(0.f, 0.f);
            curg = g;
        }
        float2 m = h2[(size_t)(row0 + i) * 64 + col2];
        acc.x += m.x; acc.y += m.y;
    }
    if (curg >= 0) {
        atomicAdd(&pooled[curg * 128 + 2 * col2], acc.x);
        atomicAdd(&pooled[curg * 128 + 2 * col2 + 1], acc.y);
    }
}

// ---------- pooling stage 2: mean + linear head ----------

__global__ __launch_bounds__(256) void k_head(const float* __restrict__ pooled,
                                              const int* __restrict__ batch,
                                              const float* __restrict__ Wl,
                                              const float* __restrict__ bl_,
                                              float* __restrict__ out) {
    int g = blockIdx.x, t = threadIdx.x;
    __shared__ int se[2];
    __shared__ float pm[128];
    __shared__ float part[256];
    if (t < 2) {
        int target = g + t;   // lower_bound(batch, target)
        int lo = 0, hi = NN;
        while (lo < hi) {
            int mid = (lo + hi) >> 1;
            if (batch[mid] < target) lo = mid + 1; else hi = mid;
        }
        se[t] = lo;
    }
    __syncthreads();
    int cntg = se[1] - se[0];
    float inv = 1.f / (float)(cntg > 0 ? cntg : 1);
    if (t < 128) pm[t] = pooled[g * 128 + t] * inv;
    __syncthreads();
    int col = t & 63, kh = t >> 6;          // 4 k-chunks of 32
    float o = 0.f;
    for (int k = kh * 32; k < kh * 32 + 32; ++k) o += pm[k] * Wl[k * OD + col];
    part[t] = o; __syncthreads();
    if (t < OD)
        out[g * OD + t] = part[t] + part[t + 64] + part[t + 128] + part[t + 192] + bl_[t];
}

// ---------- launcher ----------

extern "C" void kernel_launch(void* const* d_in, const int* in_sizes, int n_in,
                              void* d_out, int out_size, void* d_ws, size_t ws_size,
                              hipStream_t stream) {
    const float* x   = (const float*)d_in[0];
    const int*   ei  = (const int*)d_in[1];
    const int*   bat = (const int*)d_in[2];
    const float* W1  = (const float*)d_in[3];
    const float* b1  = (const float*)d_in[4];
    const float* W2  = (const float*)d_in[5];
    const float* b2  = (const float*)d_in[6];
    const float* Wl  = (const float*)d_in[7];
    const float* bl  = (const float*)d_in[8];
    float* out = (float*)d_out;
    const int* src = ei;
    const int* dst = ei + NE;

    char* w = (char*)d_ws;
    size_t off = 0;
    auto alloc = [&](size_t bytes) -> char* {
        char* p = w + off;
        off = (off + bytes + 255) & ~(size_t)255;
        return p;
    };
    int*   cnt       = (int*)alloc(NN * 4);
    int*   fill      = (int*)alloc(NN * 4);
    float* dinv      = (float*)alloc(NN * 4);
    int*   row_start = (int*)alloc((NN + 1) * 4);
    int*   chunksum  = (int*)alloc(256 * 4);
    int*   chunkoff  = (int*)alloc(256 * 4);
    float* pooled    = (float*)alloc(NG * HD * 4);
    int*   csr       = (int*)alloc((size_t)NE * 4);
    float* bufA      = (float*)alloc((size_t)NN * HD * 4);
    float* bufB      = (float*)alloc((size_t)NN * HD * 4);

    hipMemsetAsync(cnt, 0, NN * 4, stream);
    hipMemsetAsync(fill, 0, NN * 4, stream);
    hipMemsetAsync(pooled, 0, NG * HD * 4, stream);

    k_count<<<(NE + 255) / 256, 256, 0, stream>>>(dst, cnt);
    k_dinv<<<(NN + 255) / 256, 256, 0, stream>>>(cnt, dinv);
    k_chunksum<<<SCAN_BLOCKS, 256, 0, stream>>>(cnt, chunksum);
    k_scanchunks<<<1, 256, 0, stream>>>(chunksum, chunkoff, row_start);
    k_scanwrite<<<SCAN_BLOCKS, 256, 0, stream>>>(cnt, chunkoff, row_start);
    k_fill<<<(NE + 255) / 256, 256, 0, stream>>>(src, dst, row_start, fill, csr);

    // conv1: h' = (x@W1)*dinv  ->  bufA ; agg+bias+relu -> bufB
    k_gemm<<<512, 256, 0, stream>>>(x, W1, dinv, bufA, NN);
    k_agg<<<(NN + 3) / 4, 256, 0, stream>>>(bufA, row_start, csr, dinv, b1, bufB);
    // conv2
    k_gemm<<<512, 256, 0, stream>>>(bufB, W2, dinv, bufA, NN);
    k_agg<<<(NN + 3) / 4, 256, 0, stream>>>(bufA, row_start, csr, dinv, b2, bufB);
    // pool: segment-sum then mean+head
    k_pool1<<<(NN + POOL_ROWS - 1) / POOL_ROWS, 256, 0, stream>>>(bufB, bat, pooled);
    k_head<<<NG, 256, 0, stream>>>(pooled, bat, Wl, bl, out);
}

// Round 3
// 277.517 us; speedup vs baseline: 1.4883x; 1.2039x over previous
//
#include <hip/hip_runtime.h>
#include <hip/hip_bf16.h>
#include <cstdint>

#define NN 50000
#define NE 800000
#define HD 128
#define OD 64
#define NG 64
#define SCAN_CHUNK 196
#define SCAN_BLOCKS 256
#define POOL_ROWS 256

typedef unsigned int uint32;
typedef unsigned short ushort16;

// round-to-nearest-even f32 -> bf16 bits
static __device__ __forceinline__ ushort16 f2bf(float f) {
    uint32 u = __float_as_uint(f);
    u += 0x7fffu + ((u >> 16) & 1u);
    return (ushort16)(u >> 16);
}

// ---------- degree / CSR build ----------

__global__ void k_count(const int* __restrict__ dst, int* __restrict__ cnt) {
    int e = blockIdx.x * 256 + threadIdx.x;
    if (e < NE) atomicAdd(&cnt[dst[e]], 1);
}

__global__ void k_dinv(const int* __restrict__ cnt, float* __restrict__ dinv) {
    int v = blockIdx.x * 256 + threadIdx.x;
    if (v < NN) dinv[v] = rsqrtf((float)(cnt[v] + 1));  // +1 self-loop
}

__global__ void k_chunksum(const int* __restrict__ cnt, int* __restrict__ chunksum) {
    __shared__ int red[256];
    int t = threadIdx.x;
    int i = blockIdx.x * SCAN_CHUNK + t;
    int v = (t < SCAN_CHUNK && i < NN) ? cnt[i] : 0;
    red[t] = v; __syncthreads();
    for (int off = 128; off > 0; off >>= 1) {
        if (t < off) red[t] += red[t + off];
        __syncthreads();
    }
    if (t == 0) chunksum[blockIdx.x] = red[0];
}

__global__ void k_scanchunks(const int* __restrict__ chunksum, int* __restrict__ chunkoff,
                             int* __restrict__ row_start) {
    __shared__ int s[256];
    int t = threadIdx.x;
    int v = chunksum[t];
    s[t] = v; __syncthreads();
    for (int off = 1; off < 256; off <<= 1) {
        int u = (t >= off) ? s[t - off] : 0;
        __syncthreads();
        s[t] += u;
        __syncthreads();
    }
    chunkoff[t] = s[t] - v;          // exclusive
    if (t == 255) row_start[NN] = s[255];
}

__global__ void k_scanwrite(const int* __restrict__ cnt, const int* __restrict__ chunkoff,
                            int* __restrict__ row_start) {
    __shared__ int s[256];
    int t = threadIdx.x;
    int i = blockIdx.x * SCAN_CHUNK + t;
    int v = (t < SCAN_CHUNK && i < NN) ? cnt[i] : 0;
    s[t] = v; __syncthreads();
    for (int off = 1; off < 256; off <<= 1) {
        int u = (t >= off) ? s[t - off] : 0;
        __syncthreads();
        s[t] += u;
        __syncthreads();
    }
    if (t < SCAN_CHUNK && i < NN) row_start[i] = chunkoff[blockIdx.x] + s[t] - v;
}

__global__ void k_fill(const int* __restrict__ src, const int* __restrict__ dst,
                       const int* __restrict__ row_start, int* __restrict__ fill_cnt,
                       int* __restrict__ csr) {
    int e = blockIdx.x * 256 + threadIdx.x;
    if (e < NE) {
        int d = dst[e];
        int slot = row_start[d] + atomicAdd(&fill_cnt[d], 1);
        csr[slot] = src[e];
    }
}

// ---------- GEMM: hp[r] = bf16( (X[r] @ W) * dinv[r] ),  X [nrows][128] fp32 ----------

__global__ __launch_bounds__(256, 2) void k_gemm(const float* __restrict__ X,
                                                 const float* __restrict__ W,
                                                 const float* __restrict__ dinv,
                                                 ushort16* __restrict__ out, int nrows) {
    __shared__ float wl[128 * 128];   // 64 KB
    __shared__ float xl[32 * 128];    // 16 KB
    {
        float4* wl4 = (float4*)wl;
        const float4* W4 = (const float4*)W;
        for (int i = threadIdx.x; i < 128 * 32; i += 256) wl4[i] = W4[i];
    }
    const int rg = threadIdx.x >> 5;   // 0..7 : rows rg*4 .. rg*4+3
    const int cg = threadIdx.x & 31;   // cols cg*4 .. cg*4+3
    const int ntiles = (nrows + 31) >> 5;
    for (int tile = blockIdx.x; tile < ntiles; tile += gridDim.x) {
        const int row0 = tile << 5;
        __syncthreads();
        for (int i = threadIdx.x; i < 32 * 32; i += 256) {
            int rr = row0 + (i >> 5);
            ((float4*)xl)[i] = (rr < nrows) ? ((const float4*)X)[rr * 32 + (i & 31)]
                                            : make_float4(0.f, 0.f, 0.f, 0.f);
        }
        __syncthreads();
        float acc[4][4];
#pragma unroll
        for (int a = 0; a < 4; ++a)
#pragma unroll
            for (int b = 0; b < 4; ++b) acc[a][b] = 0.f;
        const float4* wl4 = (const float4*)wl;
        const float4* xl4 = (const float4*)xl;
#pragma unroll 4
        for (int kq = 0; kq < 32; ++kq) {
            float4 w0 = wl4[(4 * kq + 0) * 32 + cg];
            float4 w1 = wl4[(4 * kq + 1) * 32 + cg];
            float4 w2 = wl4[(4 * kq + 2) * 32 + cg];
            float4 w3 = wl4[(4 * kq + 3) * 32 + cg];
#pragma unroll
            for (int r = 0; r < 4; ++r) {
                float4 xv = xl4[(rg * 4 + r) * 32 + kq];
                acc[r][0] += xv.x * w0.x + xv.y * w1.x + xv.z * w2.x + xv.w * w3.x;
                acc[r][1] += xv.x * w0.y + xv.y * w1.y + xv.z * w2.y + xv.w * w3.y;
                acc[r][2] += xv.x * w0.z + xv.y * w1.z + xv.z * w2.z + xv.w * w3.z;
                acc[r][3] += xv.x * w0.w + xv.y * w1.w + xv.z * w2.w + xv.w * w3.w;
            }
        }
#pragma unroll
        for (int r = 0; r < 4; ++r) {
            int rr = row0 + rg * 4 + r;
            if (rr < nrows) {
                float dv = dinv[rr];
                ushort4 o;
                o.x = f2bf(acc[r][0] * dv);
                o.y = f2bf(acc[r][1] * dv);
                o.z = f2bf(acc[r][2] * dv);
                o.w = f2bf(acc[r][3] * dv);
                ((ushort4*)out)[(size_t)rr * 32 + cg] = o;
            }
        }
    }
}

// ---------- aggregation: out[v] = relu(dinv[v]*(hp[v] + sum_{s->v} hp[s]) + b) ----------
// hp is bf16 [NN][128]; each lane reads one uint = 2 bf16 (cols 2*lane, 2*lane+1).

static __device__ __forceinline__ void acc_bf2(float2& a, uint32 u) {
    a.x += __uint_as_float(u << 16);
    a.y += __uint_as_float(u & 0xffff0000u);
}

__global__ void k_agg(const uint32* __restrict__ hp, const int* __restrict__ row_start,
                      const int* __restrict__ csr, const float* __restrict__ dinv,
                      const float* __restrict__ bias, float* __restrict__ out) {
    int wid = threadIdx.x >> 6, lane = threadIdx.x & 63;
    int v = blockIdx.x * 4 + wid;
    if (v >= NN) return;
    float2 acc = make_float2(0.f, 0.f);
    acc_bf2(acc, hp[(size_t)v * 64 + lane]);   // self loop
    int beg = row_start[v], end = row_start[v + 1];
    int e = beg;
    // 4 independent row-gathers in flight (latency hiding)
    for (; e + 4 <= end; e += 4) {
        int s0 = csr[e], s1 = csr[e + 1], s2 = csr[e + 2], s3 = csr[e + 3];
        uint32 m0 = hp[(size_t)s0 * 64 + lane];
        uint32 m1 = hp[(size_t)s1 * 64 + lane];
        uint32 m2 = hp[(size_t)s2 * 64 + lane];
        uint32 m3 = hp[(size_t)s3 * 64 + lane];
        acc_bf2(acc, m0); acc_bf2(acc, m1); acc_bf2(acc, m2); acc_bf2(acc, m3);
    }
    for (; e < end; ++e) {
        acc_bf2(acc, hp[(size_t)csr[e] * 64 + lane]);
    }
    float dv = dinv[v];
    float2 bb = ((const float2*)bias)[lane];
    float2 o;
    o.x = fmaxf(acc.x * dv + bb.x, 0.f);
    o.y = fmaxf(acc.y * dv + bb.y, 0.f);
    ((float2*)out)[(size_t)v * 64 + lane] = o;
}

// ---------- pooling stage 1: node-parallel segment-sum into pooled[64][128] ----------

__global__ __launch_bounds__(256) void k_pool1(const float* __restrict__ h,
                                               const int* __restrict__ batch,
                                               float* __restrict__ pooled) {
    __shared__ int bl[POOL_ROWS];
    const int row0 = blockIdx.x * POOL_ROWS;
    const int rend = min(row0 + POOL_ROWS, NN);
    const int nrows = rend - row0;
    for (int i = threadIdx.x; i < nrows; i += 256) bl[i] = batch[row0 + i];
    __syncthreads();
    const int col2 = threadIdx.x & 63;      // float2 column
    const int rp   = threadIdx.x >> 6;      // 0..3
    const float2* h2 = (const float2*)h;
    float2 acc = make_float2(0.f, 0.f);
    int curg = -1;
    for (int i = rp; i < nrows; i += 4) {
        int g = bl[i];
        if (g != curg) {
            if (curg >= 0) {
                atomicAdd(&pooled[curg * 128 + 2 * col2], acc.x);
                atomicAdd(&pooled[curg * 128 + 2 * col2 + 1], acc.y);
            }
            acc = make_float2(0.f, 0.f);
            curg = g;
        }
        float2 m = h2[(size_t)(row0 + i) * 64 + col2];
        acc.x += m.x; acc.y += m.y;
    }
    if (curg >= 0) {
        atomicAdd(&pooled[curg * 128 + 2 * col2], acc.x);
        atomicAdd(&pooled[curg * 128 + 2 * col2 + 1], acc.y);
    }
}

// ---------- pooling stage 2: mean + linear head ----------

__global__ __launch_bounds__(256) void k_head(const float* __restrict__ pooled,
                                              const int* __restrict__ batch,
                                              const float* __restrict__ Wl,
                                              const float* __restrict__ bl_,
                                              float* __restrict__ out) {
    int g = blockIdx.x, t = threadIdx.x;
    __shared__ int se[2];
    __shared__ float pm[128];
    __shared__ float part[256];
    if (t < 2) {
        int target = g + t;   // lower_bound(batch, target)
        int lo = 0, hi = NN;
        while (lo < hi) {
            int mid = (lo + hi) >> 1;
            if (batch[mid] < target) lo = mid + 1; else hi = mid;
        }
        se[t] = lo;
    }
    __syncthreads();
    int cntg = se[1] - se[0];
    float inv = 1.f / (float)(cntg > 0 ? cntg : 1);
    if (t < 128) pm[t] = pooled[g * 128 + t] * inv;
    __syncthreads();
    int col = t & 63, kh = t >> 6;          // 4 k-chunks of 32
    float o = 0.f;
    for (int k = kh * 32; k < kh * 32 + 32; ++k) o += pm[k] * Wl[k * OD + col];
    part[t] = o; __syncthreads();
    if (t < OD)
        out[g * OD + t] = part[t] + part[t + 64] + part[t + 128] + part[t + 192] + bl_[t];
}

// ---------- launcher ----------

extern "C" void kernel_launch(void* const* d_in, const int* in_sizes, int n_in,
                              void* d_out, int out_size, void* d_ws, size_t ws_size,
                              hipStream_t stream) {
    const float* x   = (const float*)d_in[0];
    const int*   ei  = (const int*)d_in[1];
    const int*   bat = (const int*)d_in[2];
    const float* W1  = (const float*)d_in[3];
    const float* b1  = (const float*)d_in[4];
    const float* W2  = (const float*)d_in[5];
    const float* b2  = (const float*)d_in[6];
    const float* Wl  = (const float*)d_in[7];
    const float* bl  = (const float*)d_in[8];
    float* out = (float*)d_out;
    const int* src = ei;
    const int* dst = ei + NE;

    char* w = (char*)d_ws;
    size_t off = 0;
    auto alloc = [&](size_t bytes) -> char* {
        char* p = w + off;
        off = (off + bytes + 255) & ~(size_t)255;
        return p;
    };
    int*   cnt       = (int*)alloc(NN * 4);
    int*   fill      = (int*)alloc(NN * 4);
    float* dinv      = (float*)alloc(NN * 4);
    int*   row_start = (int*)alloc((NN + 1) * 4);
    int*   chunksum  = (int*)alloc(256 * 4);
    int*   chunkoff  = (int*)alloc(256 * 4);
    float* pooled    = (float*)alloc(NG * HD * 4);
    int*   csr       = (int*)alloc((size_t)NE * 4);
    ushort16* hp     = (ushort16*)alloc((size_t)NN * HD * 2);  // bf16 h'
    float* bufB      = (float*)alloc((size_t)NN * HD * 4);     // fp32 layer output

    hipMemsetAsync(cnt, 0, NN * 4, stream);
    hipMemsetAsync(fill, 0, NN * 4, stream);
    hipMemsetAsync(pooled, 0, NG * HD * 4, stream);

    k_count<<<(NE + 255) / 256, 256, 0, stream>>>(dst, cnt);
    k_dinv<<<(NN + 255) / 256, 256, 0, stream>>>(cnt, dinv);
    k_chunksum<<<SCAN_BLOCKS, 256, 0, stream>>>(cnt, chunksum);
    k_scanchunks<<<1, 256, 0, stream>>>(chunksum, chunkoff, row_start);
    k_scanwrite<<<SCAN_BLOCKS, 256, 0, stream>>>(cnt, chunkoff, row_start);
    k_fill<<<(NE + 255) / 256, 256, 0, stream>>>(src, dst, row_start, fill, csr);

    // conv1: hp = bf16((x@W1)*dinv) ; agg+bias+relu -> bufB (fp32)
    k_gemm<<<512, 256, 0, stream>>>(x, W1, dinv, hp, NN);
    k_agg<<<(NN + 3) / 4, 256, 0, stream>>>((const uint32*)hp, row_start, csr, dinv, b1, bufB);
    // conv2
    k_gemm<<<512, 256, 0, stream>>>(bufB, W2, dinv, hp, NN);
    k_agg<<<(NN + 3) / 4, 256, 0, stream>>>((const uint32*)hp, row_start, csr, dinv, b2, bufB);
    // pool: segment-sum then mean+head
    k_pool1<<<(NN + POOL_ROWS - 1) / POOL_ROWS, 256, 0, stream>>>(bufB, bat, pooled);
    k_head<<<NG, 256, 0, stream>>>(pooled, bat, Wl, bl, out);
}